// Round 3
// baseline (1315.747 us; speedup 1.0000x reference)
//
#include <hip/hip_runtime.h>

// Problem constants (IcoUpSampleMaxIndexLayer)
#define NB    16      // batch
#define CIN   256
#define COUT  128
#define VRAW  10242
#define NVERT 40962
#define NPAIR (VRAW * 7)   // 71694 candidate (v,k) pairs
#define OVFCAP 8192        // overflow entries for targets with n>7 (expected ~25)
#define LDS_S 40           // LDS row stride (u16) for [v][c] x-tile: conflict-free

typedef __attribute__((ext_vector_type(8))) short short8;
typedef __attribute__((ext_vector_type(4))) float floatx4;

__device__ inline unsigned short f2bf(float f) {
    unsigned u = __builtin_bit_cast(unsigned, f);
    u += 0x7fffu + ((u >> 16) & 1u);   // RNE
    return (unsigned short)(u >> 16);
}

// ---- Kernel 0: convert W (128x256 fp32) to bf16 in ws ----
__global__ __launch_bounds__(256) void convw_kernel(const float* __restrict__ W,
                                                    unsigned short* __restrict__ Wbf) {
    int i = blockIdx.x * 256 + threadIdx.x;   // 32768 elements
    Wbf[i] = f2bf(W[i]);
}

// ---- Kernel 1: build packed inverted index.
// packed[t*8] = {count, e0..e6}, entry = v<<3|k. Overflow (count>7) -> ovf list.
__global__ __launch_bounds__(256) void build_kernel(const int* __restrict__ up,
                                                    const int* __restrict__ down,
                                                    unsigned* __restrict__ packed,
                                                    unsigned* __restrict__ ovf_cnt,
                                                    unsigned* __restrict__ ovf) {
    int i = blockIdx.x * 256 + threadIdx.x;
    if (i >= NPAIR) return;
    int v = i / 7;
    int k = i - v * 7;
    int t = up[down[v] * 7 + k];
    unsigned pos = atomicAdd(&packed[(size_t)t * 8], 1u);
    if (pos < 7u) {
        packed[(size_t)t * 8 + 1 + pos] = ((unsigned)v << 3) | (unsigned)k;
    } else {
        unsigned idx = atomicAdd(ovf_cnt, 1u);
        if (idx < OVFCAP) {
            ovf[2 * idx]     = ((unsigned)t << 3) | (unsigned)k;
            ovf[2 * idx + 1] = (unsigned)v;
        }
    }
}

// ---- Kernel 2: h[b,o,v] = sum_c W[o,c] x[b,c,v] + bias[o], bf16 MFMA ----
// 128v x 128o tile per block, 256 thr (4 waves). x-tile staged [v][c] in LDS
// (stride 40 u16), double-buffered, 1 barrier/chunk, reg-prefetch 1 chunk ahead.
__global__ __launch_bounds__(256) void gemm_kernel(const float* __restrict__ x,
                                                   const unsigned short* __restrict__ Wbf,
                                                   const float* __restrict__ bias,
                                                   float* __restrict__ h) {
    __shared__ unsigned short xs[2][128 * LDS_S];   // 2 x 10240 B
    const int b    = blockIdx.y;
    const int v0   = blockIdx.x * 128;
    const int tid  = threadIdx.x;
    const int wave = tid >> 6;
    const int lane = tid & 63;
    const int mn   = lane & 15;   // A-row (o) / B-col (v) within 16-tile
    const int q    = lane >> 4;   // quad: k-offset q*8; C/D row-offset q*4
    const int vw   = wave * 32;
    const int cp   = tid >> 4;    // c-pair index 0..15 -> channels (2cp, 2cp+1)
    const int l    = tid & 15;    // v lane
    const bool full = (v0 + 128 <= VRAW);

    floatx4 acc[8][2];
#pragma unroll
    for (int ot = 0; ot < 8; ot++) { acc[ot][0] = (floatx4)0.f; acc[ot][1] = (floatx4)0.f; }

    float f0[8], f1[8];
    auto load_regs = [&](int ck) {
        const int c0 = ck * 32;
        const float* p0 = x + ((size_t)(b * CIN + c0 + 2 * cp)) * VRAW + v0 + l;
        const float* p1 = p0 + VRAW;
        if (full) {
#pragma unroll
            for (int u = 0; u < 8; u++) { f0[u] = p0[16 * u]; f1[u] = p1[16 * u]; }
        } else {
#pragma unroll
            for (int u = 0; u < 8; u++) {
                const bool ok = (v0 + l + 16 * u) < VRAW;
                f0[u] = ok ? p0[16 * u] : 0.f;
                f1[u] = ok ? p1[16 * u] : 0.f;
            }
        }
    };
    auto write_lds = [&](int buf) {
        unsigned short* base = xs[buf];
#pragma unroll
        for (int u = 0; u < 8; u++) {
            const int v = l + 16 * u;
            const unsigned pk = (unsigned)f2bf(f0[u]) | ((unsigned)f2bf(f1[u]) << 16);
            *(unsigned*)(base + v * LDS_S + 2 * cp) = pk;   // [v][c], 4B aligned
        }
    };

    load_regs(0);
    for (int ck = 0; ck < 8; ck++) {
        write_lds(ck & 1);
        __syncthreads();
        if (ck < 7) load_regs(ck + 1);   // prefetch next chunk; hidden by MFMAs
        const int c0 = ck * 32;
        const unsigned short* xb = xs[ck & 1];
        short8 bfrag[2];
#pragma unroll
        for (int vt = 0; vt < 2; vt++)
            bfrag[vt] = *(const short8*)(xb + (vw + vt * 16 + mn) * LDS_S + q * 8);
#pragma unroll
        for (int ot = 0; ot < 8; ot++) {
            short8 afrag = *(const short8*)(Wbf + (ot * 16 + mn) * CIN + c0 + q * 8);
            acc[ot][0] = __builtin_amdgcn_mfma_f32_16x16x32_bf16(afrag, bfrag[0], acc[ot][0], 0, 0, 0);
            acc[ot][1] = __builtin_amdgcn_mfma_f32_16x16x32_bf16(afrag, bfrag[1], acc[ot][1], 0, 0, 0);
        }
    }

#pragma unroll
    for (int ot = 0; ot < 8; ot++) {
#pragma unroll
        for (int vt = 0; vt < 2; vt++) {
            const int v = v0 + vw + vt * 16 + mn;
            if (v < VRAW) {
#pragma unroll
                for (int r = 0; r < 4; r++) {
                    const int o = ot * 16 + q * 4 + r;   // C/D: row = quad*4 + reg
                    h[((size_t)b * COUT + o) * VRAW + v] = acc[ot][vt][r] + bias[o];
                }
            }
        }
    }
}

// ---- Kernel 3: gather. One block per (b,o) row; mpi+h rows in LDS.
// Per target t: one 32B record -> 7 branch-free probes; winner = max v. ----
__device__ inline void probe_t(int t, const unsigned* __restrict__ packed,
                               const unsigned short* mpis, int& n, int& best) {
    const uint4 w0 = *(const uint4*)(packed + (size_t)t * 8);
    const uint4 w1 = *(const uint4*)(packed + (size_t)t * 8 + 4);
    n = (int)w0.x;
    unsigned e[7] = {w0.y, w0.z, w0.w, w1.x, w1.y, w1.z, w1.w};
    best = -1;
#pragma unroll
    for (int j = 0; j < 7; j++) {
        const int v  = (int)(e[j] >> 3);
        const int k  = (int)(e[j] & 7u);
        const int vv = v < VRAW ? v : 0;
        if (j < n && (int)mpis[vv] == k && v > best) best = v;
    }
}

__global__ __launch_bounds__(1024) void gather_kernel(const unsigned* __restrict__ packed,
                                                      const unsigned* __restrict__ ovf_cnt,
                                                      const unsigned* __restrict__ ovf,
                                                      const int* __restrict__ mpi,
                                                      const float* __restrict__ h,
                                                      float* __restrict__ y) {
    __shared__ unsigned short mpis[VRAW];   // 20484 B
    __shared__ float hs[VRAW];              // 40968 B (total 61452 < 64K)
    const int r   = blockIdx.x;             // 0..NB*COUT-1
    const int tid = threadIdx.x;

    const int*   mpiRow = mpi + (size_t)r * VRAW;
    const float* hRow   = h   + (size_t)r * VRAW;
    for (int i = tid; i < VRAW; i += 1024) {
        mpis[i] = (unsigned short)mpiRow[i];
        hs[i]   = hRow[i];
    }
    __syncthreads();

    const int novf = min((int)*ovf_cnt, OVFCAP);
    float* yRow = y + (size_t)r * NVERT;

    for (int t0 = tid; t0 < NVERT; t0 += 2048) {
        const int t1 = t0 + 1024;
        int n0, best0, n1 = 0, best1 = -1;
        probe_t(t0, packed, mpis, n0, best0);
        if (t1 < NVERT) probe_t(t1, packed, mpis, n1, best1);
        if (__any(n0 > 7 || n1 > 7)) {   // ~2% of waves; ~25 entries chip-wide
            for (int i = 0; i < novf; i++) {
                const unsigned a = ovf[2 * i];
                const int      vb = (int)ovf[2 * i + 1];
                const int      tt = (int)(a >> 3);
                const int      kk = (int)(a & 7u);
                if (n0 > 7 && tt == t0 && (int)mpis[vb] == kk && vb > best0) best0 = vb;
                if (n1 > 7 && tt == t1 && (int)mpis[vb] == kk && vb > best1) best1 = vb;
            }
        }
        yRow[t0] = (best0 >= 0) ? hs[best0] : 0.0f;
        if (t1 < NVERT) yRow[t1] = (best1 >= 0) ? hs[best1] : 0.0f;
    }
}

extern "C" void kernel_launch(void* const* d_in, const int* in_sizes, int n_in,
                              void* d_out, int out_size, void* d_ws, size_t ws_size,
                              hipStream_t stream) {
    const float* x    = (const float*)d_in[0];
    const float* W    = (const float*)d_in[1];
    const float* bias = (const float*)d_in[2];
    const int*   up   = (const int*)d_in[3];   // (NVERT, 7)
    const int*   down = (const int*)d_in[4];   // (VRAW,)
    const int*   mpi  = (const int*)d_in[5];   // (NB, COUT, VRAW)
    float* y = (float*)d_out;

    // ws layout:
    //   [0, 64K)          Wbf      (bf16 W)
    //   [64K, +1310784)   packed   (NVERT x 8 u32: count + 7 entries)
    //   ...               ovf_cnt (u32) + pad, ovf (OVFCAP x 2 u32)
    //   ...               h (NB*COUT*VRAW fp32, ~84 MB)    total ~85.3 MB
    char* ws = (char*)d_ws;
    unsigned short* Wbf     = (unsigned short*)ws;
    unsigned*       packed  = (unsigned*)(ws + 65536);
    const size_t packed_sz  = (size_t)NVERT * 8 * 4;            // 1310784
    unsigned*       ovf_cnt = (unsigned*)(ws + 65536 + packed_sz);
    unsigned*       ovf     = (unsigned*)(ws + 65536 + packed_sz + 64);
    float*          h       = (float*)(ws + 65536 + packed_sz + 64 + (size_t)OVFCAP * 8);

    // zero counts (+ovf_cnt); entry slots zeroed too (cheap, makes probes safe)
    hipMemsetAsync(packed, 0, packed_sz + 64, stream);

    convw_kernel<<<COUT * CIN / 256, 256, 0, stream>>>(W, Wbf);
    build_kernel<<<(NPAIR + 255) / 256, 256, 0, stream>>>(up, down, packed, ovf_cnt, ovf);

    dim3 ggrid((VRAW + 127) / 128, NB);
    gemm_kernel<<<ggrid, 256, 0, stream>>>(x, Wbf, bias, h);

    gather_kernel<<<NB * COUT, 1024, 0, stream>>>(packed, ovf_cnt, ovf, mpi, h, y);
}